// Round 3
// baseline (81.164 us; speedup 1.0000x reference)
//
#include <hip/hip_runtime.h>

#define Bn 32
#define Nn 256
#define Hn 128
#define En 16
#define WWC (Hn + En)   // 144
#define JT 8            // j-stripes of 512 floats (32 j) each
#define IC 8            // i-chunks of 32 rows each

typedef float v4 __attribute__((ext_vector_type(4)));

// ================= P1: gate rows + U transpose + P colsum =================
__global__ __launch_bounds__(256) void k_prep1(const int* __restrict__ adj, const float* __restrict__ U_w,
                                               const float* __restrict__ h,
                                               float* __restrict__ gate, float* __restrict__ U_T,
                                               float* __restrict__ P) {
    int bid = blockIdx.x, t = threadIdx.x;
    if (bid < Nn) {                       // gate[i][j] = (sum_b adj) > 0
        int i = bid, j = t;
        int s = 0;
        #pragma unroll
        for (int b = 0; b < Bn; ++b) s += adj[(b * Nn + i) * Nn + j];
        gate[i * Nn + j] = (s > 0) ? 1.0f : 0.0f;
    } else if (bid < Nn + 64) {           // U_T[m][o] = U_w[o][m]
        int m = (bid - Nn) * 2 + (t >> 7), o = t & 127;
        U_T[m * Hn + o] = U_w[o * Hn + m];
    } else {                              // P[b][h] = sum_i h[b,i,h]
        int b = bid - (Nn + 64);
        __shared__ float red[256];
        int hh = t & 127, half = t >> 7;
        float s = 0.f;
        for (int i = half * 128; i < half * 128 + 128; ++i)
            s += h[((size_t)b * Nn + i) * Hn + hh];
        red[t] = s;
        __syncthreads();
        if (t < 128) P[b * Hn + t] = red[t] + red[t + 128];
    }
}

// ================= P2: count/zlist + fold(A_T,Bm_T,cvec) + Q =================
__global__ __launch_bounds__(256) void k_prep2(const float* __restrict__ gate, const float* __restrict__ W_w,
                                               const float* __restrict__ W_b, const float* __restrict__ U_T,
                                               const float* __restrict__ P,
                                               float* __restrict__ count, int* __restrict__ zcnt,
                                               int* __restrict__ zlist, float* __restrict__ A_T,
                                               float* __restrict__ Bm_T, float* __restrict__ cvec,
                                               float* __restrict__ Q) {
    int bid = blockIdx.x, t = threadIdx.x;
    if (bid < Nn) {                       // column j stats
        int j = bid;
        bool z = (gate[t * Nn + j] == 0.0f);
        unsigned long long m = __ballot(z);
        int lane = t & 63, w = t >> 6;
        __shared__ int wc[4];
        if (lane == 0) wc[w] = (int)__popcll(m);
        __syncthreads();
        int off = 0;
        for (int q = 0; q < w; ++q) off += wc[q];
        if (z) zlist[j * Nn + off + (int)__popcll(m & ((1ull << lane) - 1ull))] = t;
        if (t == 0) {
            int tot = wc[0] + wc[1] + wc[2] + wc[3];
            zcnt[j] = tot;
            count[j] = (float)(Nn - tot);
        }
    } else if (bid < Nn + 145) {          // fold: A_T / Bm_T / cvec
        int r = bid - Nn;
        if (t < 128) {
            int o = t;
            float s = 0.f;
            if (r < Hn) {
                #pragma unroll 8
                for (int m = 0; m < Hn; ++m) s += U_T[m * Hn + o] * W_w[m * WWC + r];
                A_T[r * Hn + o] = s;
            } else if (r < Hn + En) {
                int e = r - Hn;
                #pragma unroll 8
                for (int m = 0; m < Hn; ++m) s += U_T[m * Hn + o] * W_w[m * WWC + Hn + e];
                Bm_T[e * Hn + o] = s;
            } else {
                #pragma unroll 8
                for (int m = 0; m < Hn; ++m) s += U_T[m * Hn + o] * W_b[m];
                cvec[o] = s;
            }
        }
    } else {                              // Q[b][m] = sum_h Wh[m,h]*P[b,h]
        int b = bid - (Nn + 145);
        if (t < 128) {
            int m = t;
            float s = 0.f;
            #pragma unroll 8
            for (int hh = 0; hh < Hn; ++hh) s += W_w[m * WWC + hh] * P[b * Hn + hh];
            Q[b * Hn + m] = s;
        }
    }
}

// ================= E: pure column-sum stream of edge_attr =================
// grid (JT*IC, Bn) = 2048 blocks x 256 threads. Block sums edge[b, ic*32..+31, stripe jt].
// epart[ic][b][jt][512] partials; NO gate in the loop (exact correction later via zlist).
__global__ __launch_bounds__(256) void k_esum(const float* __restrict__ edge, float* __restrict__ epart) {
    int jt = blockIdx.x & (JT - 1), ic = blockIdx.x >> 3, b = blockIdx.y;
    int ig = threadIdx.x >> 7, vc = threadIdx.x & 127;
    const float* p = edge + (size_t)b * (Nn * Nn * En) + (size_t)(ic * 32 + ig) * (Nn * En) + jt * 512 + vc * 4;
    v4 acc = {0.f, 0.f, 0.f, 0.f};
    #pragma unroll 8
    for (int k = 0; k < 16; ++k)
        acc += *reinterpret_cast<const v4*>(p + (size_t)(2 * k) * (Nn * En));
    __shared__ v4 sred[128];
    if (ig == 1) sred[vc] = acc;
    __syncthreads();
    if (ig == 0) {
        acc += sred[vc];
        *reinterpret_cast<v4*>(&epart[(((size_t)ic * Bn + b) * JT + jt) * 512 + vc * 4]) = acc;
    }
}

// ================= F: final GEMV + messages + exact corrections =================
// grid (JT, Bn) x 512 threads. Block: batch b, 32 columns j0..j0+31 (= stripe jt).
__global__ __launch_bounds__(512) void k_final(
    const float* __restrict__ h, const float* __restrict__ U_T, const float* __restrict__ U_b,
    const float* __restrict__ Q, const float* __restrict__ cvec, const float* __restrict__ Bm_T,
    const float* __restrict__ count, const int* __restrict__ zcnt, const int* __restrict__ zlist,
    const float* __restrict__ A_T, const float* __restrict__ epart, const float* __restrict__ edge,
    const int* __restrict__ num_nodes, float* __restrict__ out) {
    int jt = blockIdx.x, j0 = jt * 32, b = blockIdx.y, t = threadIdx.x;
    __shared__ float shj[Hn][33];     // h tile transposed, padded
    __shared__ float sbm[En][Hn];
    __shared__ float ses[32][En];
    __shared__ float sq[Hn], sc[Hn], sub[Hn], scnt[32];

    // ---- stage h tile (transposed) ----
    #pragma unroll
    for (int q = 0; q < 2; ++q) {
        int f = t + 512 * q;
        int j = f >> 5, c = f & 31;
        v4 v = *reinterpret_cast<const v4*>(&h[((size_t)b * Nn + j0 + j) * Hn + c * 4]);
        shj[c * 4 + 0][j] = v[0];
        shj[c * 4 + 1][j] = v[1];
        shj[c * 4 + 2][j] = v[2];
        shj[c * 4 + 3][j] = v[3];
    }
    {   // Bm_T
        int e = t >> 5, c = t & 31;
        *reinterpret_cast<v4*>(&sbm[e][c * 4]) = *reinterpret_cast<const v4*>(&Bm_T[e * Hn + c * 4]);
    }
    if (t < 128) {   // reduce epart partials -> e_sum tile
        v4 s = {0.f, 0.f, 0.f, 0.f};
        #pragma unroll
        for (int ic = 0; ic < IC; ++ic)
            s += *reinterpret_cast<const v4*>(&epart[(((size_t)ic * Bn + b) * JT + jt) * 512 + t * 4]);
        *reinterpret_cast<v4*>(&ses[t >> 2][(t & 3) * 4]) = s;
    }
    if (t < 32) {
        *reinterpret_cast<v4*>(&sq[t * 4])  = *reinterpret_cast<const v4*>(&Q[b * Hn + t * 4]);
        *reinterpret_cast<v4*>(&sc[t * 4])  = *reinterpret_cast<const v4*>(&cvec[t * 4]);
        *reinterpret_cast<v4*>(&sub[t * 4]) = *reinterpret_cast<const v4*>(&U_b[t * 4]);
        scnt[t] = count[j0 + t];
    }
    __syncthreads();

    int og = t & 31, o4 = og * 4, jq = t >> 5, j2 = jq * 2;
    v4 acc0 = {0.f, 0.f, 0.f, 0.f}, acc1 = {0.f, 0.f, 0.f, 0.f}, accb = {0.f, 0.f, 0.f, 0.f};
    #pragma unroll 8
    for (int m = 0; m < Hn; ++m) {
        v4 u = *reinterpret_cast<const v4*>(&U_T[m * Hn + o4]);
        acc0 += shj[m][j2] * u;
        acc1 += shj[m][j2 + 1] * u;
        accb += sq[m] * u;
    }
    int nn = num_nodes[b];
    v4 sub4 = *reinterpret_cast<v4*>(&sub[o4]);
    v4 sc4  = *reinterpret_cast<v4*>(&sc[o4]);
    #pragma unroll
    for (int jh = 0; jh < 2; ++jh) {
        int j = j0 + j2 + jh;
        v4 msg = accb;
        #pragma unroll
        for (int e = 0; e < En; ++e)
            msg += ses[j2 + jh][e] * *reinterpret_cast<v4*>(&sbm[e][o4]);
        msg += scnt[j2 + jh] * sc4;
        int zc = zcnt[j];
        if (zc > 0) {  // exact sparse corrections (normally never taken)
            v4 corr = {0.f, 0.f, 0.f, 0.f};
            for (int z = 0; z < zc; ++z) {
                int i = zlist[j * Nn + z];
                // h-side: subtract h[b,i,:]·A_T
                for (int hh = 0; hh < Hn; ++hh)
                    corr += h[((size_t)b * Nn + i) * Hn + hh] *
                            *reinterpret_cast<const v4*>(&A_T[hh * Hn + o4]);
                // e-side: subtract edge[b,i,j,:]·Bm
                for (int e = 0; e < En; ++e)
                    corr += edge[(((size_t)b * Nn + i) * Nn + j) * En + e] *
                            *reinterpret_cast<v4*>(&sbm[e][o4]);
            }
            msg -= corr;
        }
        float maskv = (j < nn) ? 1.0f : 0.0f;
        v4 res = (jh ? acc1 : acc0) + sub4 + maskv * msg;
        *reinterpret_cast<v4*>(&out[((size_t)b * Nn + j) * Hn + o4]) = res;
    }
}

extern "C" void kernel_launch(void* const* d_in, const int* in_sizes, int n_in,
                              void* d_out, int out_size, void* d_ws, size_t ws_size,
                              hipStream_t stream) {
    const float* h    = (const float*)d_in[0];
    const float* edge = (const float*)d_in[1];
    const int*   adj  = (const int*)d_in[2];
    const int*   nn   = (const int*)d_in[3];
    const float* W_w  = (const float*)d_in[4];
    const float* W_b  = (const float*)d_in[5];
    const float* U_w  = (const float*)d_in[6];
    const float* U_b  = (const float*)d_in[7];
    float* out = (float*)d_out;

    float* ws    = (float*)d_ws;
    float* gate  = ws;                 // 65536
    float* count = ws + 65536;         // 256
    int*   zcnt  = (int*)(ws + 65792); // 256
    int*   zlist = (int*)(ws + 66048); // 65536
    float* P     = ws + 131584;        // 4096
    float* U_T   = ws + 135680;        // 16384
    float* A_T   = ws + 152064;        // 16384
    float* Bm_T  = ws + 168448;        // 2048
    float* cvec  = ws + 170496;        // 128
    float* Q     = ws + 170624;        // 4096
    float* epart = ws + 174720;        // 8*32*8*512 = 1048576

    hipLaunchKernelGGL(k_prep1, dim3(Nn + 64 + Bn),  dim3(256), 0, stream, adj, U_w, h, gate, U_T, P);
    hipLaunchKernelGGL(k_prep2, dim3(Nn + 145 + Bn), dim3(256), 0, stream,
                       gate, W_w, W_b, U_T, P, count, zcnt, zlist, A_T, Bm_T, cvec, Q);
    hipLaunchKernelGGL(k_esum,  dim3(JT * IC, Bn),   dim3(256), 0, stream, edge, epart);
    hipLaunchKernelGGL(k_final, dim3(JT, Bn),        dim3(512), 0, stream,
                       h, U_T, U_b, Q, cvec, Bm_T, count, zcnt, zlist, A_T, epart, edge, nn, out);
}

// Round 4
// 49.960 us; speedup vs baseline: 1.6246x; 1.6246x over previous
//
#include <hip/hip_runtime.h>

#define Bn 32
#define Nn 256
#define Hn 128
#define En 16
#define WWC (Hn + En)   // 144
#define JT 8            // j-stripes (32 j = 512 floats each)
#define IC 8            // i-chunks of 32 rows

typedef float v4 __attribute__((ext_vector_type(4)));

// ===== K1: all independent HBM-heavy roles in ONE launch =====
// bid 0..2047: epart stream; 2048..2303: gate rows; 2304..2559: Ppart.
__global__ __launch_bounds__(256) void k_stream(const float* __restrict__ edge, const int* __restrict__ adj,
                                                const float* __restrict__ h,
                                                float* __restrict__ epart, float* __restrict__ gate,
                                                float* __restrict__ Ppart) {
    int bid = blockIdx.x, t = threadIdx.x;
    __shared__ v4 sred[128];
    if (bid < 2048) {
        int b = bid >> 6, r = bid & 63, ic = r >> 3, jt = r & 7;
        int ig = t >> 7, vc = t & 127;
        const float* p = edge + ((size_t)b << 20) + (size_t)(ic * 32 + ig) * 4096 + jt * 512 + vc * 4;
        v4 a0 = {0.f,0.f,0.f,0.f}, a1 = a0, a2 = a0, a3 = a0;
        #pragma unroll
        for (int k = 0; k < 16; ++k) {
            v4 v = *reinterpret_cast<const v4*>(p + (size_t)k * 8192);
            if ((k & 3) == 0) a0 += v; else if ((k & 3) == 1) a1 += v;
            else if ((k & 3) == 2) a2 += v; else a3 += v;
        }
        v4 s = (a0 + a1) + (a2 + a3);
        if (ig == 1) sred[vc] = s;
        __syncthreads();
        if (ig == 0) {
            s += sred[vc];
            *reinterpret_cast<v4*>(&epart[((size_t)(ic * 32 + b) * JT + jt) * 512 + vc * 4]) = s;
        }
    } else if (bid < 2304) {
        int i = bid - 2048, j = t;
        int s = 0;
        #pragma unroll
        for (int b = 0; b < Bn; ++b) s += adj[(b * Nn + i) * Nn + j];
        gate[i * Nn + j] = (s > 0) ? 1.0f : 0.0f;
    } else {
        int pb = bid - 2304, b = pb >> 3, ic = pb & 7;
        int hh = t & 127, half = t >> 7;
        float* red = reinterpret_cast<float*>(sred);
        float s = 0.f;
        #pragma unroll
        for (int k = 0; k < 16; ++k)
            s += h[((size_t)b * Nn + ic * 32 + half * 16 + k) * Hn + hh];
        red[t] = s;
        __syncthreads();
        if (t < 128) Ppart[(ic * 32 + b) * Hn + t] = red[t] + red[t + 128];
    }
}

// ===== K2: count/zlist + U transpose + P-reduce/Q =====
// bid 0..255: column stats; 256..319: U_T; 320..351: Q.
__global__ __launch_bounds__(256) void k_prep(const float* __restrict__ gate, const float* __restrict__ U_w,
                                              const float* __restrict__ W_w, const float* __restrict__ Ppart,
                                              float* __restrict__ count, int* __restrict__ zcnt,
                                              int* __restrict__ zlist, float* __restrict__ U_T,
                                              float* __restrict__ Q) {
    int bid = blockIdx.x, t = threadIdx.x;
    if (bid < Nn) {
        int j = bid;
        bool z = (gate[t * Nn + j] == 0.0f);
        unsigned long long m = __ballot(z);
        int lane = t & 63, w = t >> 6;
        __shared__ int wc[4];
        if (lane == 0) wc[w] = (int)__popcll(m);
        __syncthreads();
        int off = 0;
        for (int q = 0; q < w; ++q) off += wc[q];
        if (z) zlist[j * Nn + off + (int)__popcll(m & ((1ull << lane) - 1ull))] = t;
        if (t == 0) {
            int tot = wc[0] + wc[1] + wc[2] + wc[3];
            zcnt[j] = tot;
            count[j] = (float)(Nn - tot);
        }
    } else if (bid < Nn + 64) {
        int m = (bid - Nn) * 2 + (t >> 7), o = t & 127;
        U_T[m * Hn + o] = U_w[o * Hn + m];
    } else {
        int b = bid - (Nn + 64);
        __shared__ float sP[Hn];
        if (t < 128) {
            float p = 0.f;
            #pragma unroll
            for (int ic = 0; ic < IC; ++ic) p += Ppart[(ic * 32 + b) * Hn + t];
            sP[t] = p;
        }
        __syncthreads();
        if (t < 128) {
            float s = 0.f;
            #pragma unroll 8
            for (int hh = 0; hh < Hn; ++hh) s += W_w[t * WWC + hh] * sP[hh];
            Q[b * Hn + t] = s;
        }
    }
}

// ===== K3: final. grid (JT, Bn) x 512 =====
// z[m][j] = h[b,j,m] + mask_j*(Q[b,m] + count_j*W_b[m] + sum_e We[m,e]*E[j,e] - corr)
// out[b,j,o] = sum_m z[m][j]*U_T[m][o] + U_b[o]
__global__ __launch_bounds__(512) void k_final(
    const float* __restrict__ h, const float* __restrict__ U_T, const float* __restrict__ U_b,
    const float* __restrict__ Q, const float* __restrict__ W_w, const float* __restrict__ W_b,
    const float* __restrict__ count, const int* __restrict__ zcnt, const int* __restrict__ zlist,
    const float* __restrict__ epart, const float* __restrict__ edge,
    const int* __restrict__ num_nodes, float* __restrict__ out) {
    int jt = blockIdx.x, j0 = jt * 32, b = blockIdx.y, t = threadIdx.x;
    __shared__ float shj[Hn][33];
    __shared__ float sWe[Hn][17];
    __shared__ float sE[32][17];
    __shared__ float sQ[Hn], sWb[Hn], scnt[32], srbuf[Hn];

    // stage h tile (transposed)
    #pragma unroll
    for (int q = 0; q < 2; ++q) {
        int f = t + 512 * q;
        int j = f >> 5, c = f & 31;
        v4 v = *reinterpret_cast<const v4*>(&h[((size_t)b * Nn + j0 + j) * Hn + c * 4]);
        shj[c * 4 + 0][j] = v[0];
        shj[c * 4 + 1][j] = v[1];
        shj[c * 4 + 2][j] = v[2];
        shj[c * 4 + 3][j] = v[3];
    }
    {   // We columns of W_w
        int m = t >> 2, c = t & 3;
        v4 v = *reinterpret_cast<const v4*>(&W_w[m * WWC + Hn + c * 4]);
        sWe[m][c * 4 + 0] = v[0];
        sWe[m][c * 4 + 1] = v[1];
        sWe[m][c * 4 + 2] = v[2];
        sWe[m][c * 4 + 3] = v[3];
    }
    if (t < 128) {        // E = reduce epart
        v4 s = {0.f,0.f,0.f,0.f};
        #pragma unroll
        for (int ic = 0; ic < IC; ++ic)
            s += *reinterpret_cast<const v4*>(&epart[((size_t)(ic * 32 + b) * JT + jt) * 512 + t * 4]);
        int j = t >> 2, e4 = (t & 3) * 4;
        sE[j][e4 + 0] = s[0]; sE[j][e4 + 1] = s[1]; sE[j][e4 + 2] = s[2]; sE[j][e4 + 3] = s[3];
    } else if (t < 256) { sQ[t - 128]  = Q[b * Hn + t - 128]; }
    else if (t < 384)   { sWb[t - 256] = W_b[t - 256]; }
    else if (t < 416)   { scnt[t - 384] = count[j0 + t - 384]; }
    __syncthreads();

    int nn = num_nodes[b];
    // rare exact corrections (gate zeros)
    for (int jj = 0; jj < 32; ++jj) {
        int zc = zcnt[j0 + jj];
        if (zc > 0) {
            if (t < 128) {
                float r = 0.f;
                for (int z = 0; z < zc; ++z)
                    r += h[((size_t)b * Nn + zlist[(j0 + jj) * Nn + z]) * Hn + t];
                srbuf[t] = r;
            }
            __syncthreads();
            if (t < 128 && (j0 + jj) < nn) {
                float c = 0.f;
                #pragma unroll 8
                for (int hh = 0; hh < Hn; ++hh) c += W_w[t * WWC + hh] * srbuf[hh];
                for (int z = 0; z < zc; ++z) {
                    size_t base = (((size_t)b * Nn + zlist[(j0 + jj) * Nn + z]) * Nn + j0 + jj) * En;
                    for (int e = 0; e < En; ++e) c += sWe[t][e] * edge[base + e];
                }
                shj[t][jj] -= c;
            }
            __syncthreads();
        }
    }

    // fold y into shj
    #pragma unroll
    for (int q = 0; q < 8; ++q) {
        int f = t + 512 * q;
        int m = f >> 5, j = f & 31;
        float y = sQ[m] + scnt[j] * sWb[m];
        #pragma unroll
        for (int e = 0; e < En; ++e) y += sWe[m][e] * sE[j][e];
        if (j0 + j < nn) shj[m][j] += y;
    }
    __syncthreads();

    // GEMV: out = z . U^T + U_b
    int og = t & 31, o4 = og * 4, jq = t >> 5, j2 = jq * 2;
    v4 acc0 = {0.f,0.f,0.f,0.f}, acc1 = acc0;
    #pragma unroll 8
    for (int m = 0; m < Hn; ++m) {
        v4 u = *reinterpret_cast<const v4*>(&U_T[m * Hn + o4]);
        acc0 += shj[m][j2] * u;
        acc1 += shj[m][j2 + 1] * u;
    }
    v4 ub = *reinterpret_cast<const v4*>(&U_b[o4]);
    *reinterpret_cast<v4*>(&out[((size_t)b * Nn + j0 + j2) * Hn + o4])     = acc0 + ub;
    *reinterpret_cast<v4*>(&out[((size_t)b * Nn + j0 + j2 + 1) * Hn + o4]) = acc1 + ub;
}

extern "C" void kernel_launch(void* const* d_in, const int* in_sizes, int n_in,
                              void* d_out, int out_size, void* d_ws, size_t ws_size,
                              hipStream_t stream) {
    const float* h    = (const float*)d_in[0];
    const float* edge = (const float*)d_in[1];
    const int*   adj  = (const int*)d_in[2];
    const int*   nn   = (const int*)d_in[3];
    const float* W_w  = (const float*)d_in[4];
    const float* W_b  = (const float*)d_in[5];
    const float* U_w  = (const float*)d_in[6];
    const float* U_b  = (const float*)d_in[7];
    float* out = (float*)d_out;

    float* ws    = (float*)d_ws;
    float* gate  = ws;                  // 65536
    float* count = ws + 65536;          // 256
    int*   zcnt  = (int*)(ws + 65792);  // 256
    int*   zlist = (int*)(ws + 66048);  // 65536
    float* Ppart = ws + 131584;         // 32768
    float* U_T   = ws + 164352;         // 16384
    float* Q     = ws + 180736;         // 4096
    float* epart = ws + 184832;         // 1048576

    hipLaunchKernelGGL(k_stream, dim3(2560),      dim3(256), 0, stream, edge, adj, h, epart, gate, Ppart);
    hipLaunchKernelGGL(k_prep,   dim3(352),       dim3(256), 0, stream, gate, U_w, W_w, Ppart,
                       count, zcnt, zlist, U_T, Q);
    hipLaunchKernelGGL(k_final,  dim3(JT, Bn),    dim3(512), 0, stream,
                       h, U_T, U_b, Q, W_w, W_b, count, zcnt, zlist, epart, edge, nn, out);
}

// Round 5
// 49.015 us; speedup vs baseline: 1.6559x; 1.0193x over previous
//
#include <hip/hip_runtime.h>

#define Bn 32
#define Nn 256
#define Hn 128
#define En 16
#define WWC 144
#define JT 8            // j-stripes (32 j = 512 floats each)
#define IC 8            // i-chunks of 32 rows

typedef float v4 __attribute__((ext_vector_type(4)));

// ===== K1: ALL independent HBM-heavy + prep roles in ONE launch =====
// bid 0..2047: edge colsum partials; 2048..2303: gate; 2304..2559: Ppart; 2560..2623: U_T.
__global__ __launch_bounds__(256) void k_stream(const float* __restrict__ edge, const int* __restrict__ adj,
                                                const float* __restrict__ h, const float* __restrict__ U_w,
                                                float* __restrict__ epart, float* __restrict__ gate,
                                                float* __restrict__ Ppart, float* __restrict__ U_T) {
    int bid = blockIdx.x, t = threadIdx.x;
    __shared__ v4 sred[128];
    if (bid < 2048) {
        int b = bid >> 6, r = bid & 63, ic = r >> 3, jt = r & 7;
        int ig = t >> 7, vc = t & 127;
        const float* p = edge + ((size_t)b << 20) + (size_t)(ic * 32 + ig) * 4096 + jt * 512 + vc * 4;
        v4 a0 = {0.f,0.f,0.f,0.f}, a1 = a0, a2 = a0, a3 = a0;
        #pragma unroll
        for (int k = 0; k < 16; ++k) {
            v4 v = *reinterpret_cast<const v4*>(p + (size_t)k * 8192);
            if ((k & 3) == 0) a0 += v; else if ((k & 3) == 1) a1 += v;
            else if ((k & 3) == 2) a2 += v; else a3 += v;
        }
        v4 s = (a0 + a1) + (a2 + a3);
        if (ig == 1) sred[vc] = s;
        __syncthreads();
        if (ig == 0) {
            s += sred[vc];
            *reinterpret_cast<v4*>(&epart[((size_t)(ic * 32 + b) * JT + jt) * 512 + vc * 4]) = s;
        }
    } else if (bid < 2304) {
        int i = bid - 2048, j = t;
        int s = 0;
        #pragma unroll
        for (int b = 0; b < Bn; ++b) s += adj[(b * Nn + i) * Nn + j];
        gate[i * Nn + j] = (s > 0) ? 1.0f : 0.0f;
    } else if (bid < 2560) {
        int pb = bid - 2304, b = pb >> 3, ic = pb & 7;
        int hh = t & 127, half = t >> 7;
        float* red = reinterpret_cast<float*>(sred);
        float s = 0.f;
        #pragma unroll
        for (int k = 0; k < 16; ++k)
            s += h[((size_t)b * Nn + ic * 32 + half * 16 + k) * Hn + hh];
        red[t] = s;
        __syncthreads();
        if (t < 128) Ppart[(ic * 32 + b) * Hn + t] = red[t] + red[t + 128];
    } else {
        int m = (bid - 2560) * 2 + (t >> 7), o = t & 127;
        U_T[m * Hn + o] = U_w[o * Hn + m];
    }
}

// ===== K2: everything dependent, fused. grid (JT, Bn) x 512 =====
// z[m][j] = h[b,j,m] + mask_j*(Q[b,m] + count_j*W_b[m] + sum_e We[m,e]*E[j,e] - corr)
// out[b,j,o] = sum_m z[m][j]*U_T[m][o] + U_b[o]
__global__ __launch_bounds__(512) void k_final(
    const float* __restrict__ h, const float* __restrict__ U_T, const float* __restrict__ U_b,
    const float* __restrict__ W_w, const float* __restrict__ W_b, const float* __restrict__ gate,
    const float* __restrict__ Ppart, const float* __restrict__ epart, const float* __restrict__ edge,
    const int* __restrict__ num_nodes, float* __restrict__ out) {
    int jt = blockIdx.x, j0 = jt * 32, b = blockIdx.y, t = threadIdx.x;
    __shared__ float shj[Hn][33];      // h tile transposed (corrections+y folded in)
    __shared__ float sgate[Nn][36];    // gate tile, padded for v4 + bank rotation
    __shared__ float sWe[Hn][17];
    __shared__ float sE[32][17];
    __shared__ float sP[Hn], sQ[Hn], sWb[Hn], srbuf[Hn], sesub[En], scnt[32];
    __shared__ int szc[32];

    // ---- stage h tile (transposed) ----
    #pragma unroll
    for (int q = 0; q < 2; ++q) {
        int f = t + 512 * q, j = f >> 5, c = f & 31;
        v4 v = *reinterpret_cast<const v4*>(&h[((size_t)b * Nn + j0 + j) * Hn + c * 4]);
        shj[c * 4 + 0][j] = v[0];
        shj[c * 4 + 1][j] = v[1];
        shj[c * 4 + 2][j] = v[2];
        shj[c * 4 + 3][j] = v[3];
    }
    // ---- stage gate tile [256 i][32 j] ----
    #pragma unroll
    for (int q = 0; q < 4; ++q) {
        int f = t + 512 * q, i = f >> 3, c = f & 7;
        *reinterpret_cast<v4*>(&sgate[i][c * 4]) =
            *reinterpret_cast<const v4*>(&gate[i * Nn + j0 + c * 4]);
    }
    {   // We columns of W_w
        int m = t >> 2, c = t & 3;
        v4 v = *reinterpret_cast<const v4*>(&W_w[m * WWC + Hn + c * 4]);
        sWe[m][c * 4 + 0] = v[0];
        sWe[m][c * 4 + 1] = v[1];
        sWe[m][c * 4 + 2] = v[2];
        sWe[m][c * 4 + 3] = v[3];
    }
    if (t < 128) {          // E = reduce epart partials
        v4 s = {0.f,0.f,0.f,0.f};
        #pragma unroll
        for (int ic = 0; ic < IC; ++ic)
            s += *reinterpret_cast<const v4*>(&epart[((size_t)(ic * 32 + b) * JT + jt) * 512 + t * 4]);
        int j = t >> 2, e4 = (t & 3) * 4;
        sE[j][e4 + 0] = s[0]; sE[j][e4 + 1] = s[1]; sE[j][e4 + 2] = s[2]; sE[j][e4 + 3] = s[3];
    } else if (t < 256) {   // P[b,:] = reduce Ppart
        int hh = t - 128;
        float p = 0.f;
        #pragma unroll
        for (int ic = 0; ic < IC; ++ic) p += Ppart[(ic * 32 + b) * Hn + hh];
        sP[hh] = p;
    } else if (t < 384) {
        sWb[t - 256] = W_b[t - 256];
    }
    __syncthreads();

    if (t < 128) {          // Q[b,m] = Wh[m,:]·P[b,:]
        float s = 0.f;
        #pragma unroll 8
        for (int hh = 0; hh < Hn; ++hh) s += W_w[t * WWC + hh] * sP[hh];
        sQ[t] = s;
    } else if (t < 160) {   // per-column zero count
        int jj = t - 128, zc = 0;
        for (int i = 0; i < Nn; ++i) zc += (sgate[i][jj] == 0.0f) ? 1 : 0;
        szc[jj] = zc;
        scnt[jj] = (float)(Nn - zc);
    }
    __syncthreads();

    int nn = num_nodes[b];
    // ---- rare exact corrections (gate zeros; normally never taken) ----
    for (int jj = 0; jj < 32; ++jj) {
        if (szc[jj] > 0) {
            if (t < 128) {
                float r = 0.f;
                for (int i = 0; i < Nn; ++i)
                    if (sgate[i][jj] == 0.0f) r += h[((size_t)b * Nn + i) * Hn + t];
                srbuf[t] = r;
            } else if (t < 144) {
                int e = t - 128;
                float r = 0.f;
                for (int i = 0; i < Nn; ++i)
                    if (sgate[i][jj] == 0.0f) r += edge[(((size_t)b * Nn + i) * Nn + j0 + jj) * En + e];
                sesub[e] = r;
            }
            __syncthreads();
            if (t < 128 && (j0 + jj) < nn) {
                float c = 0.f;
                #pragma unroll 8
                for (int hh = 0; hh < Hn; ++hh) c += W_w[t * WWC + hh] * srbuf[hh];
                #pragma unroll
                for (int e = 0; e < En; ++e) c += sWe[t][e] * sesub[e];
                shj[t][jj] -= c;
            }
            __syncthreads();
        }
    }

    // ---- fold y into shj ----
    #pragma unroll
    for (int q = 0; q < 8; ++q) {
        int f = t + 512 * q, m = f >> 5, j = f & 31;
        if (j0 + j < nn) {
            float y = sQ[m] + scnt[j] * sWb[m];
            #pragma unroll
            for (int e = 0; e < En; ++e) y += sWe[m][e] * sE[j][e];
            shj[m][j] += y;
        }
    }
    __syncthreads();

    // ---- GEMV: out = z · U^T + U_b ----
    int og = t & 31, o4 = og * 4, jq = t >> 5, j2 = jq * 2;
    v4 acc0 = {0.f,0.f,0.f,0.f}, acc1 = acc0;
    #pragma unroll 8
    for (int m = 0; m < Hn; ++m) {
        v4 u = *reinterpret_cast<const v4*>(&U_T[m * Hn + o4]);
        acc0 += shj[m][j2] * u;
        acc1 += shj[m][j2 + 1] * u;
    }
    v4 ub = *reinterpret_cast<const v4*>(&U_b[o4]);
    *reinterpret_cast<v4*>(&out[((size_t)b * Nn + j0 + j2) * Hn + o4])     = acc0 + ub;
    *reinterpret_cast<v4*>(&out[((size_t)b * Nn + j0 + j2 + 1) * Hn + o4]) = acc1 + ub;
}

extern "C" void kernel_launch(void* const* d_in, const int* in_sizes, int n_in,
                              void* d_out, int out_size, void* d_ws, size_t ws_size,
                              hipStream_t stream) {
    const float* h    = (const float*)d_in[0];
    const float* edge = (const float*)d_in[1];
    const int*   adj  = (const int*)d_in[2];
    const int*   nn   = (const int*)d_in[3];
    const float* W_w  = (const float*)d_in[4];
    const float* W_b  = (const float*)d_in[5];
    const float* U_w  = (const float*)d_in[6];
    const float* U_b  = (const float*)d_in[7];
    float* out = (float*)d_out;

    float* ws    = (float*)d_ws;
    float* gate  = ws;                  // 65536 floats
    float* Ppart = ws + 65536;          // 32768
    float* U_T   = ws + 98304;          // 16384
    float* epart = ws + 114688;         // 1048576

    hipLaunchKernelGGL(k_stream, dim3(2624),   dim3(256), 0, stream,
                       edge, adj, h, U_w, epart, gate, Ppart, U_T);
    hipLaunchKernelGGL(k_final,  dim3(JT, Bn), dim3(512), 0, stream,
                       h, U_T, U_b, W_w, W_b, gate, Ppart, epart, edge, nn, out);
}